// Round 23
// baseline (303.816 us; speedup 1.0000x reference)
//
#include <hip/hip_runtime.h>

// MoE forward, MI355X. fp32 router/dispatch (exact top-k), bf16 MFMA grouped
// GEMMs, zero-elim shared-store split, persistent-CTA grids, atomic-free
// expert combine (R22: GEMMs 112->89us, MfmaUtil 17->34% after removing the
// 67MB atomicAdd RMW stream).
// R23: fuse combine into gemm2s. combine re-read+rewrote y (66MB) that
// gemm2s had just produced in registers. Now GEMM2b runs first (Eout), and
// gemm2s's epilogue emits y = shared + p0*E[s0] + p1*E[s1] directly via
// islot/scale (16 rows/thread, lookups cached across n2). -1 launch, -66MB.
// Ledger: no >4 waves/EU (R9), no dbuf (R14), no fine-phase (R6/R7),
// no mega-fusion of hetero kernels (R11/R12), persistent grids (R20).

#define NTOK 8192
#define DDIM 1024
#define HDIM 1408
#define CAP  2560
#define NROWS (NTOK + 8*CAP)   // 28672 GEMM rows: [0,8192) shared, then 8*2560 expert slots
#define YN   8388608           // NTOK*DDIM

typedef __bf16 bf16x8 __attribute__((ext_vector_type(8)));
typedef __bf16 bf16x4 __attribute__((ext_vector_type(4)));
typedef float  f32x4  __attribute__((ext_vector_type(4)));

typedef __attribute__((address_space(1))) void gvoid_t;
typedef __attribute__((address_space(3))) void svoid_t;

static __device__ __forceinline__ void load_lds16(const void* g, void* l) {
  // 16B per lane, LDS dest = wave-uniform base + lane*16 (linear)
  __builtin_amdgcn_global_load_lds((gvoid_t*)g, (svoid_t*)l, 16, 0, 0);
}

// ------- transpose+convert v3: one launch for all 4 weight tensors -------
__global__ __launch_bounds__(256) void tconv3_kernel(
    const float* __restrict__ wfc, __bf16* __restrict__ B1,
    const float* __restrict__ wsfc,
    const float* __restrict__ wproj, __bf16* __restrict__ B2,
    const float* __restrict__ wsproj) {
  __shared__ float t[64][33];
  int z = blockIdx.z, tid = threadIdx.x;
  const float* ip;
  __bf16* op;
  int R, C;
  if (z < 9) {
    if (blockIdx.y >= 16) return;          // B1 geometry: 44 x 16
    R = 1024; C = 1408;
    ip = (z < 8) ? wfc + (size_t)z * R * C : wsfc;
    op = (z < 8) ? B1 + (size_t)z * (size_t)C * R : B1 + (size_t)8 * (size_t)C * R;
  } else {
    if (blockIdx.x >= 32) return;          // B2 geometry: 32 x 22
    R = 1408; C = 1024;
    int e = z - 9;
    ip = (e < 8) ? wproj + (size_t)e * R * C : wsproj;
    op = (e < 8) ? B2 + (size_t)e * (size_t)C * R : B2 + (size_t)8 * (size_t)C * R;
  }
  int c0 = blockIdx.x * 32, r0 = blockIdx.y * 64;
  int tx = tid & 31, ty = tid >> 5;          // read: 8 rows/pass, 128B/row coalesced
#pragma unroll
  for (int k = 0; k < 8; ++k)
    t[ty + k * 8][tx] = ip[(size_t)(r0 + ty + k * 8) * C + c0 + tx];
  __syncthreads();
  int cl = tid >> 3, rq = (tid & 7) * 8;     // write: one bf16x8 (16B) per thread
  bf16x8 o;                                  // LDS bank = (8q+j+p)%32 -> 2-way (free)
#pragma unroll
  for (int j = 0; j < 8; ++j) o[j] = (__bf16)t[rq + j][cl];
  *(bf16x8*)(op + (size_t)(c0 + cl) * R + r0 + rq) = o;
}

// ------- router (+ fused x->bf16 convert): fp32 logits, softmax, top-2, renorm -------
__global__ __launch_bounds__(256) void router_kernel(
    const float* __restrict__ x, const float* __restrict__ rw,
    __bf16* __restrict__ xbf,
    int2* __restrict__ e01, float2* __restrict__ p01,
    int* __restrict__ tok_row, float* __restrict__ scale_row,
    float* __restrict__ psum_part, int* __restrict__ fcnt_part) {
  __shared__ float rwl[8 * 1024];
  __shared__ float ps[8];
  __shared__ int fc[8];
  int tid = threadIdx.x;
  if (tid < 8) { ps[tid] = 0.f; fc[tid] = 0; }
  float4* rl4 = (float4*)rwl;
  const float4* rg4 = (const float4*)rw;
#pragma unroll
  for (int j = 0; j < 8; ++j) rl4[tid + 256 * j] = rg4[tid + 256 * j];
  __syncthreads();
  int lane = tid & 63, wid = tid >> 6;
  for (int it = 0; it < 8; ++it) {
    int t = blockIdx.x * 32 + wid * 8 + it;
    const float4* xt = (const float4*)(x + (size_t)t * DDIM);
    float a[8];
#pragma unroll
    for (int e = 0; e < 8; ++e) a[e] = 0.f;
    float4 v[4];
#pragma unroll
    for (int jj = 0; jj < 4; ++jj) {
      v[jj] = xt[lane * 4 + jj];
#pragma unroll
      for (int e = 0; e < 8; ++e) {
        float4 w = rl4[e * 256 + lane * 4 + jj];
        a[e] += v[jj].x * w.x + v[jj].y * w.y + v[jj].z * w.z + v[jj].w * w.w;
      }
    }
    {
      bf16x8 o0, o1;
#pragma unroll
      for (int jj = 0; jj < 2; ++jj) {
        o0[jj * 4 + 0] = (__bf16)v[jj].x; o0[jj * 4 + 1] = (__bf16)v[jj].y;
        o0[jj * 4 + 2] = (__bf16)v[jj].z; o0[jj * 4 + 3] = (__bf16)v[jj].w;
        o1[jj * 4 + 0] = (__bf16)v[jj + 2].x; o1[jj * 4 + 1] = (__bf16)v[jj + 2].y;
        o1[jj * 4 + 2] = (__bf16)v[jj + 2].z; o1[jj * 4 + 3] = (__bf16)v[jj + 2].w;
      }
      __bf16* xo = xbf + (size_t)t * DDIM + lane * 16;
      *(bf16x8*)xo = o0;
      *(bf16x8*)(xo + 8) = o1;
    }
#pragma unroll
    for (int off = 32; off >= 1; off >>= 1)
#pragma unroll
      for (int e = 0; e < 8; ++e) a[e] += __shfl_xor(a[e], off);
    if (lane == 0) {
      int am = 0; float m = a[0];
      for (int e = 1; e < 8; ++e) if (a[e] > m) { m = a[e]; am = e; }
      float s = 0.f, ex[8];
      for (int e = 0; e < 8; ++e) { ex[e] = expf(a[e] - m); s += ex[e]; }
      float inv = 1.f / s;
      int am2 = -1; float m2 = -3.4e38f;
      for (int e = 0; e < 8; ++e) if (e != am && a[e] > m2) { m2 = a[e]; am2 = e; }
      float p0 = ex[am] * inv, p1 = ex[am2] * inv;
      float rn = 1.f / (p0 + p1 + 1e-9f);
      e01[t] = make_int2(am, am2);
      p01[t] = make_float2(p0 * rn, p1 * rn);
      tok_row[t] = t;            // shared-group rows: identity gather, weight 1
      scale_row[t] = 1.f;
      atomicAdd(&fc[am], 1);
      for (int e = 0; e < 8; ++e) atomicAdd(&ps[e], ex[e] * inv);
    }
  }
  __syncthreads();
  if (tid < 8) { psum_part[blockIdx.x * 8 + tid] = ps[tid]; fcnt_part[blockIdx.x * 8 + tid] = fc[tid]; }
}

// ------- dispatch (+stat reduce +aux +inverse map): stable rank, capacity drop -------
__global__ __launch_bounds__(256) void dispatch_kernel(
    const int2* __restrict__ e01, const float2* __restrict__ p01,
    int* __restrict__ tok_row, float* __restrict__ scale_row, int* __restrict__ counts,
    int* __restrict__ islot,
    const float* __restrict__ psum_part, const int* __restrict__ fcnt_part,
    float* __restrict__ aux_out) {
  __shared__ int lcnt[256][8];
  __shared__ float wps[4][8];
  __shared__ int wfcs[4][8];
  __shared__ float aps[8];
  __shared__ int afc[8];
  int tid = threadIdx.x, lane = tid & 63, w = tid >> 6;
  float s[8]; int c[8];
#pragma unroll
  for (int e = 0; e < 8; ++e) { s[e] = psum_part[tid * 8 + e]; c[e] = fcnt_part[tid * 8 + e]; }
#pragma unroll
  for (int off = 32; off >= 1; off >>= 1)
#pragma unroll
    for (int e = 0; e < 8; ++e) { s[e] += __shfl_xor(s[e], off); c[e] += __shfl_xor(c[e], off); }
  if (lane == 0) {
#pragma unroll
    for (int e = 0; e < 8; ++e) { wps[w][e] = s[e]; wfcs[w][e] = c[e]; }
  }
  int my[8];
#pragma unroll
  for (int e = 0; e < 8; ++e) my[e] = 0;
  int base = tid * 64;  // 256 threads * 64 entries = 16384 = N*K, contiguous => stable
  for (int j = 0; j < 64; ++j) {
    int ent = base + j; int t = ent >> 1;
    int2 ee = e01[t];
    int ex = (ent & 1) ? ee.y : ee.x;
    my[ex]++;
  }
#pragma unroll
  for (int e = 0; e < 8; ++e) lcnt[tid][e] = my[e];
  __syncthreads();
  if (tid < 8) {
    aps[tid] = wps[0][tid] + wps[1][tid] + wps[2][tid] + wps[3][tid];
    afc[tid] = wfcs[0][tid] + wfcs[1][tid] + wfcs[2][tid] + wfcs[3][tid];
    int run = 0;
    for (int i = 0; i < 256; ++i) { int cc = lcnt[i][tid]; lcnt[i][tid] = run; run += cc; }
    counts[tid] = run < CAP ? run : CAP;
  }
  __syncthreads();
  int offs[8];
#pragma unroll
  for (int e = 0; e < 8; ++e) offs[e] = lcnt[tid][e];
  for (int j = 0; j < 64; ++j) {
    int ent = base + j; int t = ent >> 1; int k = ent & 1;
    int2 ee = e01[t];
    int ex = k ? ee.y : ee.x;
    float pr = k ? p01[t].y : p01[t].x;
    int pos = offs[ex]++;
    if (pos < CAP) {
      int row = NTOK + ex * CAP + pos;
      tok_row[row] = t;
      scale_row[row] = pr;
      islot[ent] = row;          // inverse map: entry (t,k) -> kept slot row
    } else {
      islot[ent] = -1;           // dropped (keep=0 in reference)
    }
  }
  if (tid == 0) {
    float t = 0.f;
    for (int e = 0; e < 8; ++e) t += ((float)afc[e] / 8192.f) * (aps[e] / 8192.f);
    *aux_out = 0.08f * t;  // AUX_COEF * E = 0.01 * 8
  }
}

// ---------------- grouped GEMM, persistent-CTA, 128x128 tile, BK=64, 4 waves ----------------
// Per-tile body = R8 structure. RANGE: 0 = shared+expert (GEMM1), 2 =
// expert-only (GEMM2b). EPI: 1 = H-store bf16(relu^2); 4 = Eout plain bf16
// store at slot = rowbase - NTOK + grow (A is the UN-offset H base).
template <int KD, int NDT, bool GATHER, int EPI, int RANGE, int NT>
__global__ __launch_bounds__(256, 4) void gemm_kernel(
    const __bf16* __restrict__ A, const __bf16* __restrict__ B,
    __bf16* __restrict__ Hout,
    const int* __restrict__ counts, const int* __restrict__ tok_row) {
  constexpr int NCT = NDT / 128;
  constexpr int SH = NTOK / 128;   // 64 shared row-tiles
  constexpr int ET = CAP / 128;    // 20 expert row-tiles (worst case)

  __shared__ __align__(16) __bf16 As[128 * 64];   // 16 KB
  __shared__ __align__(16) __bf16 Bs[128 * 64];   // 16 KB
  __shared__ int toksL[128];

  int tid = threadIdx.x, lane = tid & 63, wid = tid >> 6;

  // tile-independent lane constants (hoisted)
  int rsub = lane >> 3, csub = lane & 7;
  int csw = (csub ^ rsub) * 16;
  int wr = wid >> 1, wc = wid & 1;
  int rA[4], rB[4], cS[2];
#pragma unroll
  for (int m2 = 0; m2 < 4; ++m2) rA[m2] = (wr * 64 + m2 * 16 + (lane & 15)) * 64;
#pragma unroll
  for (int n2 = 0; n2 < 4; ++n2) rB[n2] = (wc * 64 + n2 * 16 + (lane & 15)) * 64;
#pragma unroll
  for (int kk = 0; kk < 2; ++kk) cS[kk] = ((kk * 4 + (lane >> 4)) ^ (lane & 7)) * 8;

  for (int vt = blockIdx.x; vt < NT; vt += gridDim.x) {
    // XCD bijective remap + 4-rt chunks on the virtual tile id
    int lin = (vt & 7) * (NT >> 3) + (vt >> 3);
    int rem = lin % (4 * NCT);
    int rt = (lin / (4 * NCT)) * 4 + (rem & 3);
    int ct = rem >> 2;

    int g, i0, rowbase;
    if (RANGE == 2) { g = rt / ET; i0 = (rt % ET) << 7; rowbase = NTOK + g * CAP; }
    else {
      if (rt < SH) { g = 8; rowbase = 0; i0 = rt << 7; }
      else { int r = rt - SH; g = r / ET; i0 = (r % ET) << 7; rowbase = NTOK + g * CAP; }
    }
    int cnt = (g == 8) ? NTOK : counts[g];
    if (i0 >= cnt) continue;  // uniform skip (cheap inactive tile)

    if (GATHER) {
      __syncthreads();        // protect toksL WAR vs previous tile's staging
      if (tid < 128) {
        int i = i0 + tid; if (i > cnt - 1) i = cnt - 1;  // pad rows duplicate last valid
        toksL[tid] = tok_row[rowbase + i];
      }
      __syncthreads();
    }

    const char* aP[4];
    const char* bP[4];
    const char* Bg = (const char*)B + (size_t)g * NDT * KD * 2;
#pragma unroll
    for (int t = 0; t < 4; ++t) {
      int ia = wid * 32 + t * 8 + rsub;
      size_t arow = GATHER ? (size_t)toksL[ia] : (size_t)(rowbase + i0 + ia);
      aP[t] = (const char*)A + arow * (size_t)(KD * 2) + csw;
      int ib = ct * 128 + wid * 32 + t * 8 + rsub;
      bP[t] = Bg + (size_t)ib * (KD * 2) + csw;
    }

    f32x4 acc[4][4];
#pragma unroll
    for (int m2 = 0; m2 < 4; ++m2)
#pragma unroll
      for (int n2 = 0; n2 < 4; ++n2) acc[m2][n2] = f32x4{0.f, 0.f, 0.f, 0.f};

    // m97 structure: stage -> sync -> compute -> sync, single buffer.
    for (int k0 = 0; k0 < KD; k0 += 64) {
      size_t kb = (size_t)k0 * 2;
#pragma unroll
      for (int t = 0; t < 4; ++t) {
        load_lds16(aP[t] + kb, &As[(wid * 32 + t * 8) * 64]);
        load_lds16(bP[t] + kb, &Bs[(wid * 32 + t * 8) * 64]);
      }
      __syncthreads();   // compiler inserts s_waitcnt vmcnt(0) before barrier
#pragma unroll
      for (int kk = 0; kk < 2; ++kk) {
        bf16x8 af[4], bfr[4];
#pragma unroll
        for (int m2 = 0; m2 < 4; ++m2) af[m2] = *(const bf16x8*)&As[rA[m2] + cS[kk]];
#pragma unroll
        for (int n2 = 0; n2 < 4; ++n2) bfr[n2] = *(const bf16x8*)&Bs[rB[n2] + cS[kk]];
#pragma unroll
        for (int m2 = 0; m2 < 4; ++m2)
#pragma unroll
          for (int n2 = 0; n2 < 4; ++n2)
            acc[m2][n2] = __builtin_amdgcn_mfma_f32_16x16x32_bf16(af[m2], bfr[n2], acc[m2][n2], 0, 0, 0);
      }
      __syncthreads();   // protect LDS reuse next iteration
    }

    // epilogue; C/D frag: col = lane&15, row = (lane>>4)*4 + reg  [verified m89/m91]
#pragma unroll
    for (int m2 = 0; m2 < 4; ++m2) {
      int rb = wr * 64 + m2 * 16 + ((lane >> 4) << 2);
#pragma unroll
      for (int n2 = 0; n2 < 4; ++n2) {
        int col = ct * 128 + wc * 64 + n2 * 16 + (lane & 15);
#pragma unroll
        for (int r = 0; r < 4; ++r) {
          int grow = i0 + rb + r;
          if (grow < cnt) {
            float v = acc[m2][n2][r];
            if constexpr (EPI == 1) {
              v = fmaxf(v, 0.f);
              Hout[(size_t)(rowbase + grow) * NDT + col] = (__bf16)(v * v);
            } else {  // EPI == 4: slot-major bf16 store (combine applies prob)
              Hout[(size_t)(rowbase - NTOK + grow) * NDT + col] = (__bf16)v;
            }
          }
        }
      }
    }
  }
}

// ---- GEMM2a+combine (shared -> y), 64x128 tile, 4 waves, exactly 1 round ----
// Epilogue fuses the expert combine: y[row][col] = acc + p0*E[s0][col] +
// p1*E[s1][col] (islot/scale cached per row across n2). Requires GEMM2b
// (Eout) to have completed -- launched before this kernel, same stream.
__global__ __launch_bounds__(256, 4) void gemm2s_kernel(
    const __bf16* __restrict__ A, const __bf16* __restrict__ B,
    float* __restrict__ Yout, const __bf16* __restrict__ Eout,
    const int* __restrict__ islot, const float* __restrict__ scale_row) {
  constexpr int KD = HDIM;         // 1408
  int nwg = gridDim.x;
  int lin = (blockIdx.x & 7) * (nwg >> 3) + (blockIdx.x >> 3);
  int rem = lin % 32;
  int rt = (lin / 32) * 4 + (rem & 3);   // 0..127
  int ct = rem >> 2;                     // 0..7
  int i0 = rt << 6;                      // 64 rows per tile

  __shared__ __align__(16) __bf16 As[64 * 64];    // 8 KB
  __shared__ __align__(16) __bf16 Bs[128 * 64];   // 16 KB

  int tid = threadIdx.x, lane = tid & 63, wid = tid >> 6;

  int rsub = lane >> 3, csub = lane & 7;
  int csw = (csub ^ rsub) * 16;
  const char* gA[2];
  const char* gB[4];
  const char* Bg = (const char*)B + (size_t)8 * DDIM * KD * 2;   // shared B2 slice
#pragma unroll
  for (int q = 0; q < 2; ++q) {
    int row = (wid * 2 + q) * 8 + rsub;                 // 0..63
    gA[q] = (const char*)A + (size_t)(i0 + row) * (KD * 2) + csw;
  }
#pragma unroll
  for (int q = 0; q < 4; ++q) {
    int row = (wid * 4 + q) * 8 + rsub;                 // 0..127
    gB[q] = Bg + (size_t)(ct * 128 + row) * (KD * 2) + csw;
  }

  f32x4 acc[4][2];
#pragma unroll
  for (int m2 = 0; m2 < 4; ++m2)
#pragma unroll
    for (int n2 = 0; n2 < 2; ++n2) acc[m2][n2] = f32x4{0.f, 0.f, 0.f, 0.f};

  int rA[4], rB[2], cS[2];
#pragma unroll
  for (int m2 = 0; m2 < 4; ++m2) rA[m2] = (m2 * 16 + (lane & 15)) * 64;
#pragma unroll
  for (int n2 = 0; n2 < 2; ++n2) rB[n2] = (wid * 32 + n2 * 16 + (lane & 15)) * 64;
#pragma unroll
  for (int kk = 0; kk < 2; ++kk) cS[kk] = ((kk * 4 + (lane >> 4)) ^ (lane & 7)) * 8;

  for (int k0 = 0; k0 < KD; k0 += 64) {
    size_t kb = (size_t)k0 * 2;
#pragma unroll
    for (int q = 0; q < 2; ++q)
      load_lds16(gA[q] + kb, &As[((wid * 2 + q) * 8) * 64]);
#pragma unroll
    for (int q = 0; q < 4; ++q)
      load_lds16(gB[q] + kb, &Bs[((wid * 4 + q) * 8) * 64]);
    __syncthreads();
#pragma unroll
    for (int kk = 0; kk < 2; ++kk) {
      bf16x8 af[4], bfr[2];
#pragma unroll
      for (int m2 = 0; m2 < 4; ++m2) af[m2] = *(const bf16x8*)&As[rA[m2] + cS[kk]];
#pragma unroll
      for (int n2 = 0; n2 < 2; ++n2) bfr[n2] = *(const bf16x8*)&Bs[rB[n2] + cS[kk]];
#pragma unroll
      for (int m2 = 0; m2 < 4; ++m2)
#pragma unroll
        for (int n2 = 0; n2 < 2; ++n2)
          acc[m2][n2] = __builtin_amdgcn_mfma_f32_16x16x32_bf16(af[m2], bfr[n2], acc[m2][n2], 0, 0, 0);
    }
    __syncthreads();
  }

  // fused epilogue: y = shared + p0*E[s0] + p1*E[s1]  (identity rows)
#pragma unroll
  for (int m2 = 0; m2 < 4; ++m2) {
    int rb = m2 * 16 + ((lane >> 4) << 2);
#pragma unroll
    for (int r = 0; r < 4; ++r) {
      int row = i0 + rb + r;
      int s0 = islot[row * 2], s1 = islot[row * 2 + 1];
      float sc0 = 0.f, sc1 = 0.f;
      const __bf16* e0 = Eout;
      const __bf16* e1 = Eout;
      if (s0 >= 0) { sc0 = scale_row[s0]; e0 = Eout + (size_t)(s0 - NTOK) * DDIM; }
      if (s1 >= 0) { sc1 = scale_row[s1]; e1 = Eout + (size_t)(s1 - NTOK) * DDIM; }
#pragma unroll
      for (int n2 = 0; n2 < 2; ++n2) {
        int col = ct * 128 + wid * 32 + n2 * 16 + (lane & 15);
        float v = acc[m2][n2][r];
        if (s0 >= 0) v += sc0 * (float)e0[col];
        if (s1 >= 0) v += sc1 * (float)e1[col];
        Yout[(size_t)row * DDIM + col] = v;
      }
    }
  }
}

extern "C" void kernel_launch(void* const* d_in, const int* in_sizes, int n_in,
                              void* d_out, int out_size, void* d_ws, size_t ws_size,
                              hipStream_t stream) {
  const float* x      = (const float*)d_in[0];
  const float* rw     = (const float*)d_in[1];
  const float* wfc    = (const float*)d_in[2];
  const float* wproj  = (const float*)d_in[3];
  const float* wsfc   = (const float*)d_in[4];
  const float* wsproj = (const float*)d_in[5];
  float* y = (float*)d_out;

  char* ws = (char*)d_ws;
  size_t off = 0;
  auto alloc = [&](size_t bytes) {
    void* p = ws + off;
    off += (bytes + 1023) & ~(size_t)1023;
    return p;
  };
  __bf16* xbf      = (__bf16*)alloc((size_t)NTOK * DDIM * 2);          // 16 MB
  __bf16* B1       = (__bf16*)alloc((size_t)9 * HDIM * DDIM * 2);      // 26 MB [9][1408][1024]
  __bf16* B2       = (__bf16*)alloc((size_t)9 * DDIM * HDIM * 2);      // 26 MB [9][1024][1408]
  __bf16* H        = (__bf16*)alloc((size_t)NROWS * HDIM * 2);         // 81 MB
  __bf16* Eout     = (__bf16*)alloc((size_t)8 * CAP * DDIM * 2);       // 40 MB [8*2560][1024]
  int*    tok_row  = (int*)alloc((size_t)NROWS * 4);
  float*  scale_row= (float*)alloc((size_t)NROWS * 4);
  int*    islot    = (int*)alloc((size_t)NTOK * 2 * 4);
  int2*   e01      = (int2*)alloc((size_t)NTOK * 8);
  float2* p01      = (float2*)alloc((size_t)NTOK * 8);
  int*    counts   = (int*)alloc(1024);
  float*  psum_part= (float*)alloc(256 * 8 * 4);
  int*    fcnt_part= (int*)alloc(256 * 8 * 4);
  (void)ws_size; (void)out_size; (void)in_sizes; (void)n_in;

  tconv3_kernel<<<dim3(44, 22, 18), 256, 0, stream>>>(wfc, B1, wsfc, wproj, B2, wsproj);
  router_kernel<<<256, 256, 0, stream>>>(x, rw, xbf, e01, p01, tok_row, scale_row,
                                         psum_part, fcnt_part);
  dispatch_kernel<<<1, 256, 0, stream>>>(e01, p01, tok_row, scale_row, counts, islot,
                                         psum_part, fcnt_part, y + YN);
  // GEMM1: H = relu(gather(x) @ B1)^2 ; 2464 virtual tiles over 1024 persistent blocks
  gemm_kernel<1024, 1408, true, 1, 0, 2464><<<1024, 256, 0, stream>>>(
      xbf, B1, H, counts, tok_row);
  // GEMM2b (experts) FIRST: Eout[slot] = H_exp @ B2 (plain bf16 store)
  gemm_kernel<1408, 1024, false, 4, 2, 1280><<<1024, 256, 0, stream>>>(
      H, B2, Eout, counts, tok_row);
  // GEMM2a+combine (shared): y = H_shared @ B2s + p0*E[s0] + p1*E[s1]
  gemm2s_kernel<<<1024, 256, 0, stream>>>(H, B2, y, Eout, islot, scale_row);
}

// Round 24
// 298.432 us; speedup vs baseline: 1.0180x; 1.0180x over previous
//
#include <hip/hip_runtime.h>

// MoE forward, MI355X — FINAL configuration (R22, 299.1us best measured).
// fp32 router/dispatch (exact top-k), bf16 MFMA grouped GEMMs, zero-elim
// shared-store split, persistent-CTA grids, atomic-free expert combine.
//
// Session ledger (validated by within-session A/B):
//  + GEMM core: m97-family 128x128, BK=64, 4 waves, single-buffer,
//    4 blocks/CU (launch_bounds(256,4)); XOR chunk-swizzle (0 conflicts);
//    bijective XCD remap + 4-row-tile chunks (FETCH = unique bytes).
//  + Persistent-CTA virtual-tile grids (R20: kills straggler rounds).
//  + Atomic-free combine (R22: GEMMs 112->89us, MfmaUtil 17->34% --
//    the 67MB fp32-atomicAdd RMW stream was the single largest GEMM cost).
//  + Zero-elimination: shared GEMM plain-stores y (R16).
//  - REFUTED: >4 waves/EU (R9: VGPR cap 512/waves -> acc spill, 3.3GB
//    scratch); intra-block dbuf (R14); depth-3 counted vmcnt (R5: +11%
//    only); fine-phase interleave (R6/R7: -15..-40%); hetero mega-fusion
//    (R11/R12); combine-into-gemm2s fusion (R23: epilogue gather makes
//    gemm2s as slow as the big GEMMs, net negative).
// Not a hardware roofline (MfmaUtil 34%): remaining GEMM headroom is the
// m201-class derived-waits schedule, unreproduced here and flagged OPEN
// in the source environment.

#define NTOK 8192
#define DDIM 1024
#define HDIM 1408
#define CAP  2560
#define NROWS (NTOK + 8*CAP)   // 28672 GEMM rows: [0,8192) shared, then 8*2560 expert slots
#define YN   8388608           // NTOK*DDIM

typedef __bf16 bf16x8 __attribute__((ext_vector_type(8)));
typedef __bf16 bf16x4 __attribute__((ext_vector_type(4)));
typedef float  f32x4  __attribute__((ext_vector_type(4)));

typedef __attribute__((address_space(1))) void gvoid_t;
typedef __attribute__((address_space(3))) void svoid_t;

static __device__ __forceinline__ void load_lds16(const void* g, void* l) {
  // 16B per lane, LDS dest = wave-uniform base + lane*16 (linear)
  __builtin_amdgcn_global_load_lds((gvoid_t*)g, (svoid_t*)l, 16, 0, 0);
}

// ------- transpose+convert v3: one launch for all 4 weight tensors -------
__global__ __launch_bounds__(256) void tconv3_kernel(
    const float* __restrict__ wfc, __bf16* __restrict__ B1,
    const float* __restrict__ wsfc,
    const float* __restrict__ wproj, __bf16* __restrict__ B2,
    const float* __restrict__ wsproj) {
  __shared__ float t[64][33];
  int z = blockIdx.z, tid = threadIdx.x;
  const float* ip;
  __bf16* op;
  int R, C;
  if (z < 9) {
    if (blockIdx.y >= 16) return;          // B1 geometry: 44 x 16
    R = 1024; C = 1408;
    ip = (z < 8) ? wfc + (size_t)z * R * C : wsfc;
    op = (z < 8) ? B1 + (size_t)z * (size_t)C * R : B1 + (size_t)8 * (size_t)C * R;
  } else {
    if (blockIdx.x >= 32) return;          // B2 geometry: 32 x 22
    R = 1408; C = 1024;
    int e = z - 9;
    ip = (e < 8) ? wproj + (size_t)e * R * C : wsproj;
    op = (e < 8) ? B2 + (size_t)e * (size_t)C * R : B2 + (size_t)8 * (size_t)C * R;
  }
  int c0 = blockIdx.x * 32, r0 = blockIdx.y * 64;
  int tx = tid & 31, ty = tid >> 5;          // read: 8 rows/pass, 128B/row coalesced
#pragma unroll
  for (int k = 0; k < 8; ++k)
    t[ty + k * 8][tx] = ip[(size_t)(r0 + ty + k * 8) * C + c0 + tx];
  __syncthreads();
  int cl = tid >> 3, rq = (tid & 7) * 8;     // write: one bf16x8 (16B) per thread
  bf16x8 o;                                  // LDS bank = (8q+j+p)%32 -> 2-way (free)
#pragma unroll
  for (int j = 0; j < 8; ++j) o[j] = (__bf16)t[rq + j][cl];
  *(bf16x8*)(op + (size_t)(c0 + cl) * R + r0 + rq) = o;
}

// ------- router (+ fused x->bf16 convert): fp32 logits, softmax, top-2, renorm -------
__global__ __launch_bounds__(256) void router_kernel(
    const float* __restrict__ x, const float* __restrict__ rw,
    __bf16* __restrict__ xbf,
    int2* __restrict__ e01, float2* __restrict__ p01,
    int* __restrict__ tok_row, float* __restrict__ scale_row,
    float* __restrict__ psum_part, int* __restrict__ fcnt_part) {
  __shared__ float rwl[8 * 1024];
  __shared__ float ps[8];
  __shared__ int fc[8];
  int tid = threadIdx.x;
  if (tid < 8) { ps[tid] = 0.f; fc[tid] = 0; }
  float4* rl4 = (float4*)rwl;
  const float4* rg4 = (const float4*)rw;
#pragma unroll
  for (int j = 0; j < 8; ++j) rl4[tid + 256 * j] = rg4[tid + 256 * j];
  __syncthreads();
  int lane = tid & 63, wid = tid >> 6;
  for (int it = 0; it < 8; ++it) {
    int t = blockIdx.x * 32 + wid * 8 + it;
    const float4* xt = (const float4*)(x + (size_t)t * DDIM);
    float a[8];
#pragma unroll
    for (int e = 0; e < 8; ++e) a[e] = 0.f;
    float4 v[4];
#pragma unroll
    for (int jj = 0; jj < 4; ++jj) {
      v[jj] = xt[lane * 4 + jj];
#pragma unroll
      for (int e = 0; e < 8; ++e) {
        float4 w = rl4[e * 256 + lane * 4 + jj];
        a[e] += v[jj].x * w.x + v[jj].y * w.y + v[jj].z * w.z + v[jj].w * w.w;
      }
    }
    {
      bf16x8 o0, o1;
#pragma unroll
      for (int jj = 0; jj < 2; ++jj) {
        o0[jj * 4 + 0] = (__bf16)v[jj].x; o0[jj * 4 + 1] = (__bf16)v[jj].y;
        o0[jj * 4 + 2] = (__bf16)v[jj].z; o0[jj * 4 + 3] = (__bf16)v[jj].w;
        o1[jj * 4 + 0] = (__bf16)v[jj + 2].x; o1[jj * 4 + 1] = (__bf16)v[jj + 2].y;
        o1[jj * 4 + 2] = (__bf16)v[jj + 2].z; o1[jj * 4 + 3] = (__bf16)v[jj + 2].w;
      }
      __bf16* xo = xbf + (size_t)t * DDIM + lane * 16;
      *(bf16x8*)xo = o0;
      *(bf16x8*)(xo + 8) = o1;
    }
#pragma unroll
    for (int off = 32; off >= 1; off >>= 1)
#pragma unroll
      for (int e = 0; e < 8; ++e) a[e] += __shfl_xor(a[e], off);
    if (lane == 0) {
      int am = 0; float m = a[0];
      for (int e = 1; e < 8; ++e) if (a[e] > m) { m = a[e]; am = e; }
      float s = 0.f, ex[8];
      for (int e = 0; e < 8; ++e) { ex[e] = expf(a[e] - m); s += ex[e]; }
      float inv = 1.f / s;
      int am2 = -1; float m2 = -3.4e38f;
      for (int e = 0; e < 8; ++e) if (e != am && a[e] > m2) { m2 = a[e]; am2 = e; }
      float p0 = ex[am] * inv, p1 = ex[am2] * inv;
      float rn = 1.f / (p0 + p1 + 1e-9f);
      e01[t] = make_int2(am, am2);
      p01[t] = make_float2(p0 * rn, p1 * rn);
      tok_row[t] = t;            // shared-group rows: identity gather, weight 1
      scale_row[t] = 1.f;
      atomicAdd(&fc[am], 1);
      for (int e = 0; e < 8; ++e) atomicAdd(&ps[e], ex[e] * inv);
    }
  }
  __syncthreads();
  if (tid < 8) { psum_part[blockIdx.x * 8 + tid] = ps[tid]; fcnt_part[blockIdx.x * 8 + tid] = fc[tid]; }
}

// ------- dispatch (+stat reduce +aux +inverse map): stable rank, capacity drop -------
__global__ __launch_bounds__(256) void dispatch_kernel(
    const int2* __restrict__ e01, const float2* __restrict__ p01,
    int* __restrict__ tok_row, float* __restrict__ scale_row, int* __restrict__ counts,
    int* __restrict__ islot,
    const float* __restrict__ psum_part, const int* __restrict__ fcnt_part,
    float* __restrict__ aux_out) {
  __shared__ int lcnt[256][8];
  __shared__ float wps[4][8];
  __shared__ int wfcs[4][8];
  __shared__ float aps[8];
  __shared__ int afc[8];
  int tid = threadIdx.x, lane = tid & 63, w = tid >> 6;
  float s[8]; int c[8];
#pragma unroll
  for (int e = 0; e < 8; ++e) { s[e] = psum_part[tid * 8 + e]; c[e] = fcnt_part[tid * 8 + e]; }
#pragma unroll
  for (int off = 32; off >= 1; off >>= 1)
#pragma unroll
    for (int e = 0; e < 8; ++e) { s[e] += __shfl_xor(s[e], off); c[e] += __shfl_xor(c[e], off); }
  if (lane == 0) {
#pragma unroll
    for (int e = 0; e < 8; ++e) { wps[w][e] = s[e]; wfcs[w][e] = c[e]; }
  }
  int my[8];
#pragma unroll
  for (int e = 0; e < 8; ++e) my[e] = 0;
  int base = tid * 64;  // 256 threads * 64 entries = 16384 = N*K, contiguous => stable
  for (int j = 0; j < 64; ++j) {
    int ent = base + j; int t = ent >> 1;
    int2 ee = e01[t];
    int ex = (ent & 1) ? ee.y : ee.x;
    my[ex]++;
  }
#pragma unroll
  for (int e = 0; e < 8; ++e) lcnt[tid][e] = my[e];
  __syncthreads();
  if (tid < 8) {
    aps[tid] = wps[0][tid] + wps[1][tid] + wps[2][tid] + wps[3][tid];
    afc[tid] = wfcs[0][tid] + wfcs[1][tid] + wfcs[2][tid] + wfcs[3][tid];
    int run = 0;
    for (int i = 0; i < 256; ++i) { int cc = lcnt[i][tid]; lcnt[i][tid] = run; run += cc; }
    counts[tid] = run < CAP ? run : CAP;
  }
  __syncthreads();
  int offs[8];
#pragma unroll
  for (int e = 0; e < 8; ++e) offs[e] = lcnt[tid][e];
  for (int j = 0; j < 64; ++j) {
    int ent = base + j; int t = ent >> 1; int k = ent & 1;
    int2 ee = e01[t];
    int ex = k ? ee.y : ee.x;
    float pr = k ? p01[t].y : p01[t].x;
    int pos = offs[ex]++;
    if (pos < CAP) {
      int row = NTOK + ex * CAP + pos;
      tok_row[row] = t;
      scale_row[row] = pr;
      islot[ent] = row;          // inverse map: entry (t,k) -> kept slot row
    } else {
      islot[ent] = -1;           // dropped (keep=0 in reference)
    }
  }
  if (tid == 0) {
    float t = 0.f;
    for (int e = 0; e < 8; ++e) t += ((float)afc[e] / 8192.f) * (aps[e] / 8192.f);
    *aux_out = 0.08f * t;  // AUX_COEF * E = 0.01 * 8
  }
}

// ---------------- grouped GEMM, persistent-CTA, 128x128 tile, BK=64, 4 waves ----------------
// Per-tile body = R8 structure. RANGE: 0 = shared+expert (GEMM1), 2 =
// expert-only (GEMM2b). EPI: 1 = H-store bf16(relu^2); 4 = Eout plain bf16
// store at slot = rowbase - NTOK + grow (A is the UN-offset H base).
template <int KD, int NDT, bool GATHER, int EPI, int RANGE, int NT>
__global__ __launch_bounds__(256, 4) void gemm_kernel(
    const __bf16* __restrict__ A, const __bf16* __restrict__ B,
    __bf16* __restrict__ Hout,
    const int* __restrict__ counts, const int* __restrict__ tok_row) {
  constexpr int NCT = NDT / 128;
  constexpr int SH = NTOK / 128;   // 64 shared row-tiles
  constexpr int ET = CAP / 128;    // 20 expert row-tiles (worst case)

  __shared__ __align__(16) __bf16 As[128 * 64];   // 16 KB
  __shared__ __align__(16) __bf16 Bs[128 * 64];   // 16 KB
  __shared__ int toksL[128];

  int tid = threadIdx.x, lane = tid & 63, wid = tid >> 6;

  // tile-independent lane constants (hoisted)
  int rsub = lane >> 3, csub = lane & 7;
  int csw = (csub ^ rsub) * 16;
  int wr = wid >> 1, wc = wid & 1;
  int rA[4], rB[4], cS[2];
#pragma unroll
  for (int m2 = 0; m2 < 4; ++m2) rA[m2] = (wr * 64 + m2 * 16 + (lane & 15)) * 64;
#pragma unroll
  for (int n2 = 0; n2 < 4; ++n2) rB[n2] = (wc * 64 + n2 * 16 + (lane & 15)) * 64;
#pragma unroll
  for (int kk = 0; kk < 2; ++kk) cS[kk] = ((kk * 4 + (lane >> 4)) ^ (lane & 7)) * 8;

  for (int vt = blockIdx.x; vt < NT; vt += gridDim.x) {
    // XCD bijective remap + 4-rt chunks on the virtual tile id
    int lin = (vt & 7) * (NT >> 3) + (vt >> 3);
    int rem = lin % (4 * NCT);
    int rt = (lin / (4 * NCT)) * 4 + (rem & 3);
    int ct = rem >> 2;

    int g, i0, rowbase;
    if (RANGE == 2) { g = rt / ET; i0 = (rt % ET) << 7; rowbase = NTOK + g * CAP; }
    else {
      if (rt < SH) { g = 8; rowbase = 0; i0 = rt << 7; }
      else { int r = rt - SH; g = r / ET; i0 = (r % ET) << 7; rowbase = NTOK + g * CAP; }
    }
    int cnt = (g == 8) ? NTOK : counts[g];
    if (i0 >= cnt) continue;  // uniform skip (cheap inactive tile)

    if (GATHER) {
      __syncthreads();        // protect toksL WAR vs previous tile's staging
      if (tid < 128) {
        int i = i0 + tid; if (i > cnt - 1) i = cnt - 1;  // pad rows duplicate last valid
        toksL[tid] = tok_row[rowbase + i];
      }
      __syncthreads();
    }

    const char* aP[4];
    const char* bP[4];
    const char* Bg = (const char*)B + (size_t)g * NDT * KD * 2;
#pragma unroll
    for (int t = 0; t < 4; ++t) {
      int ia = wid * 32 + t * 8 + rsub;
      size_t arow = GATHER ? (size_t)toksL[ia] : (size_t)(rowbase + i0 + ia);
      aP[t] = (const char*)A + arow * (size_t)(KD * 2) + csw;
      int ib = ct * 128 + wid * 32 + t * 8 + rsub;
      bP[t] = Bg + (size_t)ib * (KD * 2) + csw;
    }

    f32x4 acc[4][4];
#pragma unroll
    for (int m2 = 0; m2 < 4; ++m2)
#pragma unroll
      for (int n2 = 0; n2 < 4; ++n2) acc[m2][n2] = f32x4{0.f, 0.f, 0.f, 0.f};

    // m97 structure: stage -> sync -> compute -> sync, single buffer.
    for (int k0 = 0; k0 < KD; k0 += 64) {
      size_t kb = (size_t)k0 * 2;
#pragma unroll
      for (int t = 0; t < 4; ++t) {
        load_lds16(aP[t] + kb, &As[(wid * 32 + t * 8) * 64]);
        load_lds16(bP[t] + kb, &Bs[(wid * 32 + t * 8) * 64]);
      }
      __syncthreads();   // compiler inserts s_waitcnt vmcnt(0) before barrier
#pragma unroll
      for (int kk = 0; kk < 2; ++kk) {
        bf16x8 af[4], bfr[4];
#pragma unroll
        for (int m2 = 0; m2 < 4; ++m2) af[m2] = *(const bf16x8*)&As[rA[m2] + cS[kk]];
#pragma unroll
        for (int n2 = 0; n2 < 4; ++n2) bfr[n2] = *(const bf16x8*)&Bs[rB[n2] + cS[kk]];
#pragma unroll
        for (int m2 = 0; m2 < 4; ++m2)
#pragma unroll
          for (int n2 = 0; n2 < 4; ++n2)
            acc[m2][n2] = __builtin_amdgcn_mfma_f32_16x16x32_bf16(af[m2], bfr[n2], acc[m2][n2], 0, 0, 0);
      }
      __syncthreads();   // protect LDS reuse next iteration
    }

    // epilogue; C/D frag: col = lane&15, row = (lane>>4)*4 + reg  [verified m89/m91]
#pragma unroll
    for (int m2 = 0; m2 < 4; ++m2) {
      int rb = wr * 64 + m2 * 16 + ((lane >> 4) << 2);
#pragma unroll
      for (int n2 = 0; n2 < 4; ++n2) {
        int col = ct * 128 + wc * 64 + n2 * 16 + (lane & 15);
#pragma unroll
        for (int r = 0; r < 4; ++r) {
          int grow = i0 + rb + r;
          if (grow < cnt) {
            float v = acc[m2][n2][r];
            if constexpr (EPI == 1) {
              v = fmaxf(v, 0.f);
              Hout[(size_t)(rowbase + grow) * NDT + col] = (__bf16)(v * v);
            } else {  // EPI == 4: slot-major bf16 store (combine applies prob)
              Hout[(size_t)(rowbase - NTOK + grow) * NDT + col] = (__bf16)v;
            }
          }
        }
      }
    }
  }
}

// ---------------- GEMM2a (shared -> y plain store), 64x128 tile, 4 waves, exactly 1 round ----------------
__global__ __launch_bounds__(256, 4) void gemm2s_kernel(
    const __bf16* __restrict__ A, const __bf16* __restrict__ B,
    float* __restrict__ Yout) {
  constexpr int KD = HDIM;         // 1408
  int nwg = gridDim.x;
  int lin = (blockIdx.x & 7) * (nwg >> 3) + (blockIdx.x >> 3);
  int rem = lin % 32;
  int rt = (lin / 32) * 4 + (rem & 3);   // 0..127
  int ct = rem >> 2;                     // 0..7
  int i0 = rt << 6;                      // 64 rows per tile

  __shared__ __align__(16) __bf16 As[64 * 64];    // 8 KB
  __shared__ __align__(16) __bf16 Bs[128 * 64];   // 16 KB

  int tid = threadIdx.x, lane = tid & 63, wid = tid >> 6;

  int rsub = lane >> 3, csub = lane & 7;
  int csw = (csub ^ rsub) * 16;
  const char* gA[2];
  const char* gB[4];
  const char* Bg = (const char*)B + (size_t)8 * DDIM * KD * 2;   // shared B2 slice
#pragma unroll
  for (int q = 0; q < 2; ++q) {
    int row = (wid * 2 + q) * 8 + rsub;                 // 0..63
    gA[q] = (const char*)A + (size_t)(i0 + row) * (KD * 2) + csw;
  }
#pragma unroll
  for (int q = 0; q < 4; ++q) {
    int row = (wid * 4 + q) * 8 + rsub;                 // 0..127
    gB[q] = Bg + (size_t)(ct * 128 + row) * (KD * 2) + csw;
  }

  f32x4 acc[4][2];
#pragma unroll
  for (int m2 = 0; m2 < 4; ++m2)
#pragma unroll
    for (int n2 = 0; n2 < 2; ++n2) acc[m2][n2] = f32x4{0.f, 0.f, 0.f, 0.f};

  int rA[4], rB[2], cS[2];
#pragma unroll
  for (int m2 = 0; m2 < 4; ++m2) rA[m2] = (m2 * 16 + (lane & 15)) * 64;
#pragma unroll
  for (int n2 = 0; n2 < 2; ++n2) rB[n2] = (wid * 32 + n2 * 16 + (lane & 15)) * 64;
#pragma unroll
  for (int kk = 0; kk < 2; ++kk) cS[kk] = ((kk * 4 + (lane >> 4)) ^ (lane & 7)) * 8;

  for (int k0 = 0; k0 < KD; k0 += 64) {
    size_t kb = (size_t)k0 * 2;
#pragma unroll
    for (int q = 0; q < 2; ++q)
      load_lds16(gA[q] + kb, &As[((wid * 2 + q) * 8) * 64]);
#pragma unroll
    for (int q = 0; q < 4; ++q)
      load_lds16(gB[q] + kb, &Bs[((wid * 4 + q) * 8) * 64]);
    __syncthreads();
#pragma unroll
    for (int kk = 0; kk < 2; ++kk) {
      bf16x8 af[4], bfr[2];
#pragma unroll
      for (int m2 = 0; m2 < 4; ++m2) af[m2] = *(const bf16x8*)&As[rA[m2] + cS[kk]];
#pragma unroll
      for (int n2 = 0; n2 < 2; ++n2) bfr[n2] = *(const bf16x8*)&Bs[rB[n2] + cS[kk]];
#pragma unroll
      for (int m2 = 0; m2 < 4; ++m2)
#pragma unroll
        for (int n2 = 0; n2 < 2; ++n2)
          acc[m2][n2] = __builtin_amdgcn_mfma_f32_16x16x32_bf16(af[m2], bfr[n2], acc[m2][n2], 0, 0, 0);
    }
    __syncthreads();
  }

#pragma unroll
  for (int m2 = 0; m2 < 4; ++m2) {
    int rb = m2 * 16 + ((lane >> 4) << 2);
#pragma unroll
    for (int n2 = 0; n2 < 2; ++n2) {
      int col = ct * 128 + wid * 32 + n2 * 16 + (lane & 15);
#pragma unroll
      for (int r = 0; r < 4; ++r)
        Yout[(size_t)(i0 + rb + r) * DDIM + col] = acc[m2][n2][r];
    }
  }
}

// ---------------- combine: y[t] += p0*E[slot0] + p1*E[slot1] ----------------
// One block per token; thread handles one float4 (col = tid*4). Memory-bound:
// 33MB y read + 33MB E gathered read + 33MB y write ~= 100MB.
__global__ __launch_bounds__(256) void combine_kernel(
    float* __restrict__ y, const __bf16* __restrict__ Eout,
    const int* __restrict__ islot, const float* __restrict__ scale_row) {
  int t = blockIdx.x, tid = threadIdx.x;
  int s0 = islot[t * 2], s1 = islot[t * 2 + 1];
  float4* yp = (float4*)(y + (size_t)t * DDIM) + tid;
  float4 a = *yp;
  if (s0 >= 0) {
    float sc = scale_row[s0];
    bf16x4 e = *((const bf16x4*)(Eout + (size_t)(s0 - NTOK) * DDIM) + tid);
    a.x += sc * (float)e[0]; a.y += sc * (float)e[1];
    a.z += sc * (float)e[2]; a.w += sc * (float)e[3];
  }
  if (s1 >= 0) {
    float sc = scale_row[s1];
    bf16x4 e = *((const bf16x4*)(Eout + (size_t)(s1 - NTOK) * DDIM) + tid);
    a.x += sc * (float)e[0]; a.y += sc * (float)e[1];
    a.z += sc * (float)e[2]; a.w += sc * (float)e[3];
  }
  *yp = a;
}

extern "C" void kernel_launch(void* const* d_in, const int* in_sizes, int n_in,
                              void* d_out, int out_size, void* d_ws, size_t ws_size,
                              hipStream_t stream) {
  const float* x      = (const float*)d_in[0];
  const float* rw     = (const float*)d_in[1];
  const float* wfc    = (const float*)d_in[2];
  const float* wproj  = (const float*)d_in[3];
  const float* wsfc   = (const float*)d_in[4];
  const float* wsproj = (const float*)d_in[5];
  float* y = (float*)d_out;

  char* ws = (char*)d_ws;
  size_t off = 0;
  auto alloc = [&](size_t bytes) {
    void* p = ws + off;
    off += (bytes + 1023) & ~(size_t)1023;
    return p;
  };
  __bf16* xbf      = (__bf16*)alloc((size_t)NTOK * DDIM * 2);          // 16 MB
  __bf16* B1       = (__bf16*)alloc((size_t)9 * HDIM * DDIM * 2);      // 26 MB [9][1408][1024]
  __bf16* B2       = (__bf16*)alloc((size_t)9 * DDIM * HDIM * 2);      // 26 MB [9][1024][1408]
  __bf16* H        = (__bf16*)alloc((size_t)NROWS * HDIM * 2);         // 81 MB
  __bf16* Eout     = (__bf16*)alloc((size_t)8 * CAP * DDIM * 2);       // 40 MB [8*2560][1024]
  int*    tok_row  = (int*)alloc((size_t)NROWS * 4);
  float*  scale_row= (float*)alloc((size_t)NROWS * 4);
  int*    islot    = (int*)alloc((size_t)NTOK * 2 * 4);
  int2*   e01      = (int2*)alloc((size_t)NTOK * 8);
  float2* p01      = (float2*)alloc((size_t)NTOK * 8);
  int*    counts   = (int*)alloc(1024);
  float*  psum_part= (float*)alloc(256 * 8 * 4);
  int*    fcnt_part= (int*)alloc(256 * 8 * 4);
  (void)ws_size; (void)out_size; (void)in_sizes; (void)n_in;

  tconv3_kernel<<<dim3(44, 22, 18), 256, 0, stream>>>(wfc, B1, wsfc, wproj, B2, wsproj);
  router_kernel<<<256, 256, 0, stream>>>(x, rw, xbf, e01, p01, tok_row, scale_row,
                                         psum_part, fcnt_part);
  dispatch_kernel<<<1, 256, 0, stream>>>(e01, p01, tok_row, scale_row, counts, islot,
                                         psum_part, fcnt_part, y + YN);
  // GEMM1: H = relu(gather(x) @ B1)^2 ; 2464 virtual tiles over 1024 persistent blocks
  gemm_kernel<1024, 1408, true, 1, 0, 2464><<<1024, 256, 0, stream>>>(
      xbf, B1, H, counts, tok_row);
  // GEMM2a (shared): y = H_shared @ B2s (plain store; 1024 blocks = exactly 1 round)
  gemm2s_kernel<<<1024, 256, 0, stream>>>(H, B2, y);
  // GEMM2b (experts): Eout[slot] = H_exp @ B2 (plain bf16 store, no atomics)
  // NOTE: A = H un-offset; kernel's rowbase = NTOK + g*CAP addresses the
  // expert region of H internally.
  gemm_kernel<1408, 1024, false, 4, 2, 1280><<<1024, 256, 0, stream>>>(
      H, B2, Eout, counts, tok_row);
  // combine: y[t] += p0*E[s0] + p1*E[s1] via inverse map
  combine_kernel<<<NTOK, 256, 0, stream>>>(y, Eout, islot, scale_row);
}